// Round 6
// baseline (518.902 us; speedup 1.0000x reference)
//
#include <hip/hip_runtime.h>
#include <math.h>

// MMD, Gaussian kernel, bandwidth=512. X:[8192,512] Y:[8192,512] fp32.
// S_AB = sum_ij exp(-||a_i-b_j||^2/512); final combine emulates the
// reference's fp32 logsumexp->exp->combine path (see finalize_kernel).
//
// GEMM on bf16 MFMA via split-bf16 3-product (hi*hi' + hi*lo' + lo*hi').
// Round-6: kill the LDS pipeline. The pre-swizzled workspace layout
// [kstep][point][16 bf16] IS fragment order: a wave's frag = contiguous
// 1 KB global_load_dwordx4. Direct-load fragments into VGPRs with 2-deep
// register prefetch -> ZERO barriers in the K-loop (rounds 4/5 plateaued
// at 45% MfmaUtil on the vmcnt(0)+s_barrier drain of global_load_lds).
// Per-element accumulation order unchanged -> d2 bits identical.

#define D      512
#define BTM    128
#define BTN    256
#define BK     16
#define KSTEPS (D / BK)

typedef __attribute__((ext_vector_type(8)))  short  short8;   // 8 bf16
typedef __attribute__((ext_vector_type(16))) float  f32x16;   // 32x32 acc

__device__ __forceinline__ unsigned short bf16_rne(float x) {
    unsigned u = __float_as_uint(x);
    return (unsigned short)((u + 0x7fffu + ((u >> 16) & 1u)) >> 16);
}
__device__ __forceinline__ float bf16_f32(unsigned short b) {
    return __uint_as_float(((unsigned)b) << 16);
}
__device__ __forceinline__ void split8(const float v[8], uint4& hi, uint4& lo) {
    unsigned h[8], l[8];
    #pragma unroll
    for (int j = 0; j < 8; j++) {
        unsigned short bh = bf16_rne(v[j]);
        float r = v[j] - bf16_f32(bh);          // exact (Sterbenz)
        unsigned short bl = bf16_rne(r);
        h[j] = bh; l[j] = bl;
    }
    hi.x = h[0] | (h[1] << 16); hi.y = h[2] | (h[3] << 16);
    hi.z = h[4] | (h[5] << 16); hi.w = h[6] | (h[7] << 16);
    lo.x = l[0] | (l[1] << 16); lo.y = l[2] | (l[3] << 16);
    lo.z = l[4] | (l[5] << 16); lo.w = l[6] | (l[7] << 16);
}

// one-time split: src[npts][512] fp32 -> hi/lo as [kstep][point][16 bf16]
__global__ __launch_bounds__(256)
void convert_kernel(const float* __restrict__ src, uint4* __restrict__ hi,
                    uint4* __restrict__ lo, int npts) {
    const int ks = blockIdx.y;
    const int p  = blockIdx.x * 256 + threadIdx.x;
    if (p >= npts) return;
    const float* s = src + (size_t)p * D + ks * BK;
    float v[16];
    *(float4*)&v[0]  = *(const float4*)(s);
    *(float4*)&v[4]  = *(const float4*)(s + 4);
    *(float4*)&v[8]  = *(const float4*)(s + 8);
    *(float4*)&v[12] = *(const float4*)(s + 12);
    uint4 h0, l0, h1, l1;
    split8(&v[0], h0, l0);
    split8(&v[8], h1, l1);
    size_t u = ((size_t)ks * npts + p) * 2;     // uint4 units
    hi[u] = h0; hi[u + 1] = h1;
    lo[u] = l0; lo[u + 1] = l1;
}

__global__ __launch_bounds__(256)
void row_norms_kernel(const float* __restrict__ X, const float* __restrict__ Y,
                      float* __restrict__ X2, float* __restrict__ Y2, int N, int M) {
    const int wave = threadIdx.x >> 6;
    const int lane = threadIdx.x & 63;
    const int row  = blockIdx.x * 4 + wave;
    const float* src; float* dst; int r;
    if (row < N)          { src = X; dst = X2; r = row; }
    else if (row < N + M) { src = Y; dst = Y2; r = row - N; }
    else return;
    const float* p = src + (size_t)r * D;
    float s = 0.f;
    #pragma unroll
    for (int c = 0; c < D; c += 64) {
        float v = p[c + lane];
        s = fmaf(v, v, s);
    }
    #pragma unroll
    for (int off = 32; off > 0; off >>= 1) s += __shfl_down(s, off);
    if (lane == 0) dst[r] = s;
}

// order-preserving float<->uint key (for atomicMin over f32)
__device__ inline unsigned float_key(float f) {
    unsigned u = __float_as_uint(f);
    return (u & 0x80000000u) ? ~u : (u | 0x80000000u);
}
__device__ inline float key_float(unsigned k) {
    return __uint_as_float((k & 0x80000000u) ? (k ^ 0x80000000u) : ~k);
}

struct Frags { short8 ah[2], al[2], bh[4], bl[4]; };

// grid (64,32,3): z=0 XX (sym), z=1 XY, z=2 YY (sym)
__global__ __launch_bounds__(256, 2)
void pair_exp_sum_kernel(const uint4* __restrict__ Xhi, const uint4* __restrict__ Xlo,
                         const uint4* __restrict__ Yhi, const uint4* __restrict__ Ylo,
                         const float* __restrict__ X2, const float* __restrict__ Y2,
                         double* __restrict__ accum, unsigned* __restrict__ minkey,
                         int N, int M) {
    const int z = blockIdx.z;
    const uint4 *Ahi, *Alo, *Bhi, *Blo; const float *An, *Bn; bool sym; int na, nb;
    if (z == 0)      { Ahi=Xhi; Alo=Xlo; Bhi=Xhi; Blo=Xlo; An=X2; Bn=X2; sym=true;  na=N; nb=N; }
    else if (z == 1) { Ahi=Xhi; Alo=Xlo; Bhi=Yhi; Blo=Ylo; An=X2; Bn=Y2; sym=false; na=N; nb=M; }
    else             { Ahi=Yhi; Alo=Ylo; Bhi=Yhi; Blo=Ylo; An=Y2; Bn=Y2; sym=true;  na=M; nb=M; }
    const int bi = blockIdx.x, bj = blockIdx.y;
    if (sym && (2 * bj + 1) < bi) return;       // both 128-col halves below diag

    __shared__ float  smN[BTM + BTN];
    __shared__ double wsum[4];
    __shared__ float  wmin[4];

    const int tid  = threadIdx.x;
    const int wave = tid >> 6, lane = tid & 63;
    const int wy = wave >> 1, wx = wave & 1;    // 2x2 waves, each 64x128
    const int row0 = bi * BTM, col0 = bj * BTN;

    if (tid < BTM) smN[tid] = An[row0 + tid];
    smN[BTM + tid] = Bn[col0 + tid];            // all 256 threads
    __syncthreads();                            // only block-wide sync til epilogue

    const size_t strideA = (size_t)na * 2;      // short8 units per kstep
    const size_t strideB = (size_t)nb * 2;

    // frag sources: lane -> point (lane&31), k-half (lane>>5); contiguous
    // 1 KB per wave per frag -> coalesced global_load_dwordx4 (saddr form)
    const int fp = lane & 31, fh = lane >> 5;
    size_t au[2], bu[4];
    #pragma unroll
    for (int g = 0; g < 2; g++) au[g] = (size_t)(row0 + 64 * wy + 32 * g + fp) * 2 + fh;
    #pragma unroll
    for (int c = 0; c < 4; c++) bu[c] = (size_t)(col0 + 128 * wx + 32 * c + fp) * 2 + fh;

    const short8* pAhi = (const short8*)Ahi;
    const short8* pAlo = (const short8*)Alo;
    const short8* pBhi = (const short8*)Bhi;
    const short8* pBlo = (const short8*)Blo;

    f32x16 acc[2][4];
    #pragma unroll
    for (int g = 0; g < 2; g++)
        #pragma unroll
        for (int c = 0; c < 4; c++)
            #pragma unroll
            for (int i = 0; i < 16; i++) acc[g][c][i] = 0.f;

    auto load = [&](int ks, Frags& f) {
        size_t ka = (size_t)ks * strideA, kb = (size_t)ks * strideB;
        #pragma unroll
        for (int g = 0; g < 2; g++) { f.ah[g] = pAhi[ka + au[g]]; f.al[g] = pAlo[ka + au[g]]; }
        #pragma unroll
        for (int c = 0; c < 4; c++) { f.bh[c] = pBhi[kb + bu[c]]; f.bl[c] = pBlo[kb + bu[c]]; }
    };
    auto compute = [&](const Frags& f) {
        // same per-element order as rounds 3-5: all hh, all hl, all lh
        #pragma unroll
        for (int g = 0; g < 2; g++)
            #pragma unroll
            for (int c = 0; c < 4; c++)
                acc[g][c] = __builtin_amdgcn_mfma_f32_32x32x16_bf16(f.ah[g], f.bh[c], acc[g][c], 0, 0, 0);
        #pragma unroll
        for (int g = 0; g < 2; g++)
            #pragma unroll
            for (int c = 0; c < 4; c++)
                acc[g][c] = __builtin_amdgcn_mfma_f32_32x32x16_bf16(f.ah[g], f.bl[c], acc[g][c], 0, 0, 0);
        #pragma unroll
        for (int g = 0; g < 2; g++)
            #pragma unroll
            for (int c = 0; c < 4; c++)
                acc[g][c] = __builtin_amdgcn_mfma_f32_32x32x16_bf16(f.al[g], f.bh[c], acc[g][c], 0, 0, 0);
    };

    // register ping-pong, 1-step prefetch, no barriers: compiler is free to
    // hoist loads and emit fine-grained s_waitcnt vmcnt(N)
    Frags F0, F1;
    load(0, F0);
    for (int ks = 0; ks + 2 < KSTEPS; ks += 2) {
        load(ks + 1, F1);
        compute(F0);
        load(ks + 2, F0);
        compute(F1);
    }
    load(KSTEPS - 1, F1);
    compute(F0);
    compute(F1);

    // per-wave triangular weight (col-128-half granularity)
    float wgt = 1.f;
    if (sym) {
        int cblk = 2 * bj + wx;
        wgt = (cblk > bi) ? 2.f : (cblk == bi ? 1.f : 0.f);
    }

    // epilogue: d2 = |a|^2+|b|^2-2ab; min d2; sum exp(-d2/512)
    // C/D layout (m74/m101): col=lane&31, row=(reg&3)+8*(reg>>2)+4*(lane>>5)
    double s = 0.0;
    float dmin = 1e30f;
    if (wgt != 0.f) {
        const float* rowN = &smN[64 * wy];
        const float* colN = &smN[BTM + 128 * wx];
        #pragma unroll
        for (int g = 0; g < 2; g++)
            #pragma unroll
            for (int c = 0; c < 4; c++) {
                float cn = colN[32 * c + fp];
                float rs = 0.f;
                #pragma unroll
                for (int r = 0; r < 16; r++) {
                    int r32 = (r & 3) + 8 * (r >> 2) + 4 * fh;
                    float d2 = rowN[32 * g + r32] + cn - 2.0f * acc[g][c][r];
                    dmin = fminf(dmin, d2);
                    rs += expf(d2 * (-1.0f / 512.0f));
                }
                s += (double)rs;
            }
        s *= (double)wgt;
    }

    #pragma unroll
    for (int off = 32; off > 0; off >>= 1) {
        s += __shfl_down(s, off);
        dmin = fminf(dmin, __shfl_down(dmin, off));
    }
    if (lane == 0) { wsum[wave] = s; wmin[wave] = dmin; }
    __syncthreads();
    if (tid == 0) {
        double tot = wsum[0] + wsum[1] + wsum[2] + wsum[3];
        atomicAdd(&accum[z], tot);
        float bm = fminf(fminf(wmin[0], wmin[1]), fminf(wmin[2], wmin[3]));
        atomicMin(&minkey[z], float_key(bm));
    }
}

__global__ void finalize_kernel(const double* __restrict__ accum,
                                const unsigned* __restrict__ minkey,
                                float* __restrict__ out, int N, int M) {
    if (threadIdx.x == 0 && blockIdx.x == 0) {
        float Sp[3];
        #pragma unroll
        for (int z = 0; z < 3; z++) {
            float m = key_float(minkey[z]) * (-1.0f / 512.0f);
            double Sshift = accum[z] * exp(-(double)m);
            float r = (float)log(Sshift);       // correctly-rounded f32 log
            float lse = r + m;                  // fp32 add, as jax
            Sp[z] = (float)exp((double)lse);    // correctly-rounded f32 exp
        }
        float nf  = (float)N, mf = (float)M;
        float nn1 = (float)((double)N * (double)(N - 1));
        float mm1 = (float)((double)M * (double)(M - 1));
        float nm  = (float)((double)N * (double)M);
        float xx = (Sp[0] - nf) / nn1;
        float xy =  Sp[1]       / nm;
        float yy = (Sp[2] - mf) / mm1;
        out[0] = xx - 2.0f * xy + yy;
    }
}

extern "C" void kernel_launch(void* const* d_in, const int* in_sizes, int n_in,
                              void* d_out, int out_size, void* d_ws, size_t ws_size,
                              hipStream_t stream) {
    const float* X = (const float*)d_in[0];
    const float* Y = (const float*)d_in[1];
    const int N = in_sizes[0] / D;
    const int M = in_sizes[1] / D;

    // ws: accum(3 f64)@0; minkey(3 u32)@32; X2@64; Y2; then 256B-aligned
    // swizzled bf16 arrays Xhi,Xlo,Yhi,Ylo (N*D*2 B each; 32 MB total)
    double*   accum  = (double*)d_ws;
    unsigned* minkey = (unsigned*)((char*)d_ws + 32);
    float*    X2     = (float*)((char*)d_ws + 64);
    float*    Y2     = X2 + N;
    size_t off = (64 + (size_t)(N + M) * 4 + 255) & ~(size_t)255;
    size_t asz = (size_t)N * D * 2;             // bytes per array (N==M)
    uint4* Xhi = (uint4*)((char*)d_ws + off);
    uint4* Xlo = (uint4*)((char*)d_ws + off + asz);
    uint4* Yhi = (uint4*)((char*)d_ws + off + 2 * asz);
    uint4* Ylo = (uint4*)((char*)d_ws + off + 3 * asz);

    hipMemsetAsync(accum, 0, 32, stream);
    hipMemsetAsync(minkey, 0xFF, 32, stream);

    row_norms_kernel<<<(N + M + 3) / 4, 256, 0, stream>>>(X, Y, X2, Y2, N, M);
    convert_kernel<<<dim3((N + 255) / 256, KSTEPS), 256, 0, stream>>>(X, Xhi, Xlo, N);
    convert_kernel<<<dim3((M + 255) / 256, KSTEPS), 256, 0, stream>>>(Y, Yhi, Ylo, M);

    dim3 grid(N / BTM, M / BTN, 3);
    pair_exp_sum_kernel<<<grid, 256, 0, stream>>>(Xhi, Xlo, Yhi, Ylo, X2, Y2,
                                                  accum, minkey, N, M);

    finalize_kernel<<<1, 64, 0, stream>>>(accum, minkey, (float*)d_out, N, M);
}